// Round 2
// baseline (347.468 us; speedup 1.0000x reference)
//
#include <hip/hip_runtime.h>
#include <stdint.h>

#define ALPHA 0.2f

typedef __bf16 bf16x8 __attribute__((ext_vector_type(8)));
typedef float f32x4 __attribute__((ext_vector_type(4)));

__device__ __forceinline__ uint32_t rotl32(uint32_t x, int r) {
  return (x << r) | (x >> (32 - r));
}

// JAX threefry2x32, key = (0, 42) -> ks = [0, 42, 0x1BD11BDA^42 = 0x1BD11BF0]
// PARTITIONABLE semantics (default since jax 0.4.36+): for 32-bit random_bits,
// counters are (hi32(f), lo32(f)) = (0, f) and bits = x0_final ^ x1_final.
__device__ __forceinline__ uint32_t tf_mix(uint32_t f) {
  const uint32_t ks1 = 42u, ks2 = 0x1BD11BF0u;
  uint32_t x0 = 0u;        // c0(=0) + ks0(=0)
  uint32_t x1 = f + ks1;
#define TFR(r) { x0 += x1; x1 = rotl32(x1, r); x1 ^= x0; }
  TFR(13) TFR(15) TFR(26) TFR(6)  x0 += ks1; x1 += ks2 + 1u;
  TFR(17) TFR(29) TFR(16) TFR(24) x0 += ks2; x1 += 0u  + 2u;
  TFR(13) TFR(15) TFR(26) TFR(6)  x0 += 0u;  x1 += ks1 + 3u;
  TFR(17) TFR(29) TFR(16) TFR(24) x0 += ks1; x1 += ks2 + 4u;
  TFR(13) TFR(15) TFR(26) TFR(6)  x0 += ks2; x1 += 0u  + 5u;
#undef TFR
  return x0 ^ x1;
}

__device__ __forceinline__ unsigned short f2bf(float f) {  // RNE, no NaN here
  uint32_t u = __float_as_uint(f);
  return (unsigned short)((u + 0x7fffu + ((u >> 16) & 1u)) >> 16);
}

// K1: Wh = batch @ w (fp32), also bf16 transposed copy WhbT[128][8192]; init s2max key.
__global__ __launch_bounds__(256) void wh_kernel(
    const float* __restrict__ batch, const float* __restrict__ w,
    float* __restrict__ Wh, unsigned short* __restrict__ WhbT, uint32_t* __restrict__ s2key) {
  int t = threadIdx.x;
  int i0 = blockIdx.x * 32;
  int d = t & 127, rg = t >> 7;
  int ib = i0 + rg * 16;
  if (blockIdx.x == 0 && t == 0) *s2key = 0u;
  float acc[16];
#pragma unroll
  for (int r = 0; r < 16; ++r) acc[r] = 0.f;
  for (int k = 0; k < 128; k += 4) {
    float wv0 = w[(k + 0) * 128 + d];
    float wv1 = w[(k + 1) * 128 + d];
    float wv2 = w[(k + 2) * 128 + d];
    float wv3 = w[(k + 3) * 128 + d];
#pragma unroll
    for (int r = 0; r < 16; ++r) {
      float4 b4 = *(const float4*)&batch[(ib + r) * 128 + k];
      acc[r] = fmaf(b4.w, wv3, fmaf(b4.z, wv2, fmaf(b4.y, wv1, fmaf(b4.x, wv0, acc[r]))));
    }
  }
  unsigned short hb[16];
#pragma unroll
  for (int r = 0; r < 16; ++r) {
    Wh[(ib + r) * 128 + d] = acc[r];
    hb[r] = f2bf(acc[r]);
  }
  uint32_t pk[8];
#pragma unroll
  for (int q = 0; q < 8; ++q) pk[q] = (uint32_t)hb[2 * q] | ((uint32_t)hb[2 * q + 1] << 16);
  uint4* dst = (uint4*)&WhbT[d * 8192 + ib];
  dst[0] = make_uint4(pk[0], pk[1], pk[2], pk[3]);
  dst[1] = make_uint4(pk[4], pk[5], pk[6], pk[7]);
}

// K2: s1 = Wh@a1, s2 = Wh@a2, atomic-max key of s2.
__global__ __launch_bounds__(256) void s_kernel(
    const float* __restrict__ Wh, const float* __restrict__ a,
    float* __restrict__ s1, float* __restrict__ s2, uint32_t* __restrict__ s2key) {
  int t = threadIdx.x;
  int i = blockIdx.x * 32 + (t >> 3);
  int seg = t & 7, c0 = seg * 16;
  const float* wr = &Wh[i * 128 + c0];
  float p1 = 0.f, p2 = 0.f;
#pragma unroll
  for (int c = 0; c < 16; ++c) {
    float v = wr[c];
    p1 = fmaf(v, a[c0 + c], p1);
    p2 = fmaf(v, a[128 + c0 + c], p2);
  }
  p1 += __shfl_xor(p1, 1, 64); p1 += __shfl_xor(p1, 2, 64); p1 += __shfl_xor(p1, 4, 64);
  p2 += __shfl_xor(p2, 1, 64); p2 += __shfl_xor(p2, 2, 64); p2 += __shfl_xor(p2, 4, 64);
  if (seg == 0) { s1[i] = p1; s2[i] = p2; }
  float v = (seg == 0) ? p2 : -3.4e38f;
#pragma unroll
  for (int m = 1; m <= 32; m <<= 1) v = fmaxf(v, __shfl_xor(v, m, 64));
  if ((t & 63) == 0) {
    uint32_t b = __float_as_uint(v);
    uint32_t key = (b & 0x80000000u) ? ~b : (b | 0x80000000u);
    atomicMax(s2key, key);
  }
}

// K3: fused scores + softmax + threefry dropout + PV (bf16 MFMA) + elu.
// Block: 512 thr = 8 waves. Rows: 16 lower (i0..i0+15) + 16 paired upper (+4096).
__global__ __launch_bounds__(512) void gat_main(
    const float* __restrict__ s1, const float* __restrict__ s2g,
    const uint32_t* __restrict__ s2key, const unsigned short* __restrict__ WhbT,
    float* __restrict__ out) {
  __shared__ __align__(16) float s2lds[8192];
  __shared__ __align__(16) unsigned short plds[32 * 64];
  __shared__ float zlds[32];
  int t = threadIdx.x;
  int i0 = blockIdx.x * 16;

  for (int k = t; k < 2048; k += 512) ((float4*)s2lds)[k] = ((const float4*)s2g)[k];

  uint32_t kk = *s2key;
  uint32_t mb = (kk & 0x80000000u) ? (kk ^ 0x80000000u) : ~kk;
  float s2max = __uint_as_float(mb);

  // phase-A mapping: 16 row-pairs x 32 j-threads (2 cols each)
  int rl = t >> 5, jt = t & 31;
  float s1lo = s1[i0 + rl], s1hi = s1[i0 + 4096 + rl];
  float xlo = s1lo + s2max; float mlo = fmaxf(xlo, ALPHA * xlo);
  float xhi = s1hi + s2max; float mhi = fmaxf(xhi, ALPHA * xhi);
  float zlo = 0.f, zhi = 0.f;
  uint32_t cbase = (uint32_t)(i0 + rl) * 8192u + (uint32_t)(jt * 2);
  // swizzled LDS write offsets (halfword units): granule(16B) ^= row&7
  int j0loc = jt * 2;
  int pw_lo = rl * 64 + ((((j0loc >> 3)) ^ (rl & 7)) << 3) + (j0loc & 7);
  int pw_hi = pw_lo + 16 * 64;

  // phase-B mapping: wave -> (m-half, n-quarter)
  int w = t >> 6, lane = t & 63;
  int mh = w & 1, nq = w >> 1;
  int arow = mh * 16 + (lane & 15);
  int g = lane >> 4;
  int aoff0 = arow * 64 + (((0 + g) ^ (arow & 7)) << 3);
  int aoff1 = arow * 64 + (((4 + g) ^ (arow & 7)) << 3);
  const unsigned short* bb0 = WhbT + (nq * 32 + (lane & 15)) * 8192 + g * 8;       // nf=0
  const unsigned short* bb1 = bb0 + 16 * 8192;                                     // nf=1
  f32x4 acc0 = {0.f, 0.f, 0.f, 0.f}, acc1 = {0.f, 0.f, 0.f, 0.f};
  const uint32_t KTH = 0xE6666600u;  // keep <=> bits < (7549747<<9)  (u < 0.9f)

  __syncthreads();

  for (int jb = 0; jb < 8192; jb += 64) {
    // ---- phase A: P tile [32][64] bf16 into swizzled LDS ----
    float sj0 = s2lds[jb + j0loc], sj1 = s2lds[jb + j0loc + 1];
    uint32_t c = cbase + (uint32_t)jb;
    // partitionable threefry bits per element (flat idx; hi rows at +2^25)
    uint32_t bLo0 = tf_mix(c);
    uint32_t bLo1 = tf_mix(c + 1u);
    uint32_t bHi0 = tf_mix(c + 0x2000000u);
    uint32_t bHi1 = tf_mix(c + 0x2000001u);
    float x, e;
    x = s1lo + sj0; e = fmaxf(x, ALPHA * x); float p00 = __expf(e - mlo);
    x = s1lo + sj1; e = fmaxf(x, ALPHA * x); float p01 = __expf(e - mlo);
    x = s1hi + sj0; e = fmaxf(x, ALPHA * x); float p10 = __expf(e - mhi);
    x = s1hi + sj1; e = fmaxf(x, ALPHA * x); float p11 = __expf(e - mhi);
    zlo += p00 + p01; zhi += p10 + p11;
    uint32_t packlo = (uint32_t)f2bf(bLo0 < KTH ? p00 : 0.f) |
                      ((uint32_t)f2bf(bLo1 < KTH ? p01 : 0.f) << 16);
    uint32_t packhi = (uint32_t)f2bf(bHi0 < KTH ? p10 : 0.f) |
                      ((uint32_t)f2bf(bHi1 < KTH ? p11 : 0.f) << 16);
    *(uint32_t*)&plds[pw_lo] = packlo;
    *(uint32_t*)&plds[pw_hi] = packhi;
    __syncthreads();
    // ---- phase B: out[32][128] += P @ Wh[jb:jb+64][:] ----
    bf16x8 A0 = *(const bf16x8*)&plds[aoff0];
    bf16x8 A1 = *(const bf16x8*)&plds[aoff1];
    const unsigned short* bp0 = bb0 + jb;
    const unsigned short* bp1 = bb1 + jb;
    bf16x8 B00 = *(const bf16x8*)(bp0);
    bf16x8 B10 = *(const bf16x8*)(bp0 + 32);
    bf16x8 B01 = *(const bf16x8*)(bp1);
    bf16x8 B11 = *(const bf16x8*)(bp1 + 32);
    acc0 = __builtin_amdgcn_mfma_f32_16x16x32_bf16(A0, B00, acc0, 0, 0, 0);
    acc0 = __builtin_amdgcn_mfma_f32_16x16x32_bf16(A1, B10, acc0, 0, 0, 0);
    acc1 = __builtin_amdgcn_mfma_f32_16x16x32_bf16(A0, B01, acc1, 0, 0, 0);
    acc1 = __builtin_amdgcn_mfma_f32_16x16x32_bf16(A1, B11, acc1, 0, 0, 0);
    __syncthreads();
  }

  // Z reduce across the 32 j-threads of each row (within half-wave)
#pragma unroll
  for (int m = 1; m <= 16; m <<= 1) {
    zlo += __shfl_xor(zlo, m, 64);
    zhi += __shfl_xor(zhi, m, 64);
  }
  if (jt == 0) { zlds[rl] = zlo; zlds[16 + rl] = zhi; }
  __syncthreads();

  // epilogue: scale by 1/(0.9 Z), elu, store (C/D layout: col=lane&15, row=4*(lane>>4)+reg)
#pragma unroll
  for (int nf = 0; nf < 2; ++nf) {
    f32x4 a = nf ? acc1 : acc0;
    int d = nq * 32 + nf * 16 + (lane & 15);
#pragma unroll
    for (int reg = 0; reg < 4; ++reg) {
      int r = mh * 16 + (lane >> 4) * 4 + reg;
      float v = a[reg] / (0.9f * zlds[r]);
      v = v > 0.f ? v : expm1f(v);
      int grow = (r < 16) ? (i0 + r) : (i0 + 4096 + (r - 16));
      out[grow * 128 + d] = v;
    }
  }
}

extern "C" void kernel_launch(void* const* d_in, const int* in_sizes, int n_in,
                              void* d_out, int out_size, void* d_ws, size_t ws_size,
                              hipStream_t stream) {
  const float* batch = (const float*)d_in[0];
  const float* w = (const float*)d_in[1];
  const float* a = (const float*)d_in[2];
  float* out = (float*)d_out;
  char* ws = (char*)d_ws;
  float* Wh = (float*)ws;                                   // 4 MB
  unsigned short* WhbT = (unsigned short*)(ws + (4 << 20)); // 2 MB
  float* s1 = (float*)(ws + (6 << 20));                     // 32 KB
  float* s2 = (float*)(ws + (6 << 20) + 32768);             // 32 KB
  uint32_t* s2key = (uint32_t*)(ws + (6 << 20) + 65536);    // 4 B

  wh_kernel<<<256, 256, 0, stream>>>(batch, w, Wh, WhbT, s2key);
  s_kernel<<<256, 256, 0, stream>>>(Wh, a, s1, s2, s2key);
  gat_main<<<256, 512, 0, stream>>>(s1, s2, s2key, WhbT, out);
}

// Round 3
// 213.998 us; speedup vs baseline: 1.6237x; 1.6237x over previous
//
#include <hip/hip_runtime.h>
#include <stdint.h>

#define ALPHA 0.2f

typedef __bf16 bf16x8 __attribute__((ext_vector_type(8)));
typedef float f32x4 __attribute__((ext_vector_type(4)));

__device__ __forceinline__ uint32_t rotl32(uint32_t x, int r) {
  return __builtin_amdgcn_alignbit(x, x, 32 - r);  // single v_alignbit_b32
}

// JAX threefry2x32, key=(0,42), partitionable semantics: counters (0, f),
// bits = x0_final ^ x1_final.  (verified: round-2 pass)
__device__ __forceinline__ uint32_t tf_mix(uint32_t f) {
  const uint32_t ks1 = 42u, ks2 = 0x1BD11BF0u;
  uint32_t x0 = 0u;
  uint32_t x1 = f + ks1;
#define TFR(r) { x0 += x1; x1 = rotl32(x1, r); x1 ^= x0; }
  TFR(13) TFR(15) TFR(26) TFR(6)  x0 += ks1; x1 += ks2 + 1u;
  TFR(17) TFR(29) TFR(16) TFR(24) x0 += ks2; x1 += 0u  + 2u;
  TFR(13) TFR(15) TFR(26) TFR(6)  x0 += 0u;  x1 += ks1 + 3u;
  TFR(17) TFR(29) TFR(16) TFR(24) x0 += ks1; x1 += ks2 + 4u;
  TFR(13) TFR(15) TFR(26) TFR(6)  x0 += ks2; x1 += 0u  + 5u;
#undef TFR
  return x0 ^ x1;
}

__device__ __forceinline__ unsigned short f2bf(float f) {  // RNE
  uint32_t u = __float_as_uint(f);
  return (unsigned short)((u + 0x7fffu + ((u >> 16) & 1u)) >> 16);
}

// K1: Wh = batch @ w (fp32, kept in LDS only), bf16 WhbT[128][8192] to global,
// fused s1/s2 (fp32 dot with a1/a2) and block-max of s2 -> atomicMax key.
__global__ __launch_bounds__(256) void wh_kernel(
    const float* __restrict__ batch, const float* __restrict__ w,
    const float* __restrict__ a, unsigned short* __restrict__ WhbT,
    float* __restrict__ s1, float* __restrict__ s2, uint32_t* __restrict__ s2key) {
  __shared__ float whlds[32][128];  // 16 KB
  int t = threadIdx.x;
  int i0 = blockIdx.x * 32;
  int d = t & 127, rg = t >> 7;
  int ib = i0 + rg * 16;
  float acc[16];
#pragma unroll
  for (int r = 0; r < 16; ++r) acc[r] = 0.f;
  for (int k = 0; k < 128; k += 4) {
    float wv0 = w[(k + 0) * 128 + d];
    float wv1 = w[(k + 1) * 128 + d];
    float wv2 = w[(k + 2) * 128 + d];
    float wv3 = w[(k + 3) * 128 + d];
#pragma unroll
    for (int r = 0; r < 16; ++r) {
      float4 b4 = *(const float4*)&batch[(ib + r) * 128 + k];
      acc[r] = fmaf(b4.w, wv3, fmaf(b4.z, wv2, fmaf(b4.y, wv1, fmaf(b4.x, wv0, acc[r]))));
    }
  }
  unsigned short hb[16];
#pragma unroll
  for (int r = 0; r < 16; ++r) {
    whlds[rg * 16 + r][d] = acc[r];
    hb[r] = f2bf(acc[r]);
  }
  uint32_t pk[8];
#pragma unroll
  for (int q = 0; q < 8; ++q) pk[q] = (uint32_t)hb[2 * q] | ((uint32_t)hb[2 * q + 1] << 16);
  uint4* dst = (uint4*)&WhbT[d * 8192 + ib];
  dst[0] = make_uint4(pk[0], pk[1], pk[2], pk[3]);
  dst[1] = make_uint4(pk[4], pk[5], pk[6], pk[7]);
  __syncthreads();
  // s-phase: row rr reduced by 8 threads x 16 d each
  int rr = t >> 3, seg = t & 7, c0 = seg * 16;
  const float* wr = &whlds[rr][c0];
  float p1 = 0.f, p2 = 0.f;
#pragma unroll
  for (int c = 0; c < 16; ++c) {
    float v = wr[c];
    p1 = fmaf(v, a[c0 + c], p1);
    p2 = fmaf(v, a[128 + c0 + c], p2);
  }
  p1 += __shfl_xor(p1, 1, 64); p1 += __shfl_xor(p1, 2, 64); p1 += __shfl_xor(p1, 4, 64);
  p2 += __shfl_xor(p2, 1, 64); p2 += __shfl_xor(p2, 2, 64); p2 += __shfl_xor(p2, 4, 64);
  if (seg == 0) { s1[i0 + rr] = p1; s2[i0 + rr] = p2; }
  float v = (seg == 0) ? p2 : -3.4e38f;
#pragma unroll
  for (int m = 1; m <= 32; m <<= 1) v = fmaxf(v, __shfl_xor(v, m, 64));
  if ((t & 63) == 0) {
    uint32_t b = __float_as_uint(v);
    uint32_t key = (b & 0x80000000u) ? ~b : (b | 0x80000000u);
    atomicMax(s2key, key);
  }
}

// K2: fused scores + softmax-numerator + threefry dropout + PV partial.
// Grid: 512 row-blocks x 2 j-chunks. Block: 512 thr = 8 waves, 16 rows,
// chunk of 4096 cols. Partials accumulated with atomicAdd (exactly 2
// commutative contributions per location -> deterministic).
__global__ __launch_bounds__(512, 8) void gat_main(
    const float* __restrict__ s1, const float* __restrict__ s2g,
    const uint32_t* __restrict__ s2key, const unsigned short* __restrict__ WhbT,
    float* __restrict__ pacc, float* __restrict__ pz) {
  __shared__ __align__(16) float s2c[4096];           // 16 KB chunk of s2
  __shared__ __align__(16) unsigned short plds[16 * 64];  // 2 KB P tile
  int t = threadIdx.x;
  int rb = blockIdx.x >> 1, ck = blockIdx.x & 1;
  int R0 = rb * 16, C0 = ck * 4096;

  for (int k = t; k < 1024; k += 512)
    ((float4*)s2c)[k] = ((const float4*)(s2g + C0))[k];

  uint32_t kk = *s2key;
  uint32_t mb = (kk & 0x80000000u) ? (kk ^ 0x80000000u) : ~kk;
  float s2max = __uint_as_float(mb);

  // phase-A mapping: 16 rows x 32 j-threads (2 cols each)
  int r = t >> 5, jt = t & 31;
  float s1r = s1[R0 + r];
  float xm = s1r + s2max;
  float mr = fmaxf(xm, ALPHA * xm);   // exact row max (monotone leaky)
  float z = 0.f;
  uint32_t cbase = (uint32_t)(R0 + r) * 8192u + (uint32_t)(C0 + 2 * jt);
  int j0loc = 2 * jt;
  int pw = r * 64 + ((((j0loc >> 3)) ^ (r & 7)) << 3) + (j0loc & 7);

  // phase-B mapping: wave w owns d-tile w (16 cols of out)
  int w = t >> 6, lane = t & 63;
  int arow = lane & 15, g = lane >> 4;
  int aoff0 = arow * 64 + ((g ^ (arow & 7)) << 3);
  int aoff1 = arow * 64 + (((g + 4) ^ (arow & 7)) << 3);
  const unsigned short* bbase = WhbT + (w * 16 + (lane & 15)) * 8192 + C0 + g * 8;
  f32x4 acc = {0.f, 0.f, 0.f, 0.f};
  const uint32_t KTH = 0xE6666600u;  // keep <=> bits < 7549747<<9

  __syncthreads();

  for (int jb = 0; jb < 4096; jb += 64) {
    // prefetch B fragments (L2) — consumed after the barrier
    bf16x8 B0 = *(const bf16x8*)(bbase + jb);
    bf16x8 B1 = *(const bf16x8*)(bbase + jb + 32);
    float sj0 = s2c[jb + j0loc], sj1 = s2c[jb + j0loc + 1];
    uint32_t c = cbase + (uint32_t)jb;
    uint32_t b0 = tf_mix(c), b1 = tf_mix(c + 1u);
    float x0 = s1r + sj0; float e0 = fmaxf(x0, ALPHA * x0); float p0 = __expf(e0 - mr);
    float x1 = s1r + sj1; float e1 = fmaxf(x1, ALPHA * x1); float p1 = __expf(e1 - mr);
    z += p0 + p1;
    uint32_t pk = (uint32_t)f2bf(b0 < KTH ? p0 : 0.f) |
                  ((uint32_t)f2bf(b1 < KTH ? p1 : 0.f) << 16);
    *(uint32_t*)&plds[pw] = pk;
    __syncthreads();
    bf16x8 A0 = *(const bf16x8*)&plds[aoff0];
    bf16x8 A1 = *(const bf16x8*)&plds[aoff1];
    acc = __builtin_amdgcn_mfma_f32_16x16x32_bf16(A0, B0, acc, 0, 0, 0);
    acc = __builtin_amdgcn_mfma_f32_16x16x32_bf16(A1, B1, acc, 0, 0, 0);
    __syncthreads();
  }

  // Z partial: reduce across 32 j-threads (stays within 32-lane half)
#pragma unroll
  for (int m = 1; m <= 16; m <<= 1) z += __shfl_xor(z, m, 64);
  if (jt == 0) atomicAdd(&pz[R0 + r], z);

  // acc: C/D layout col=lane&15, row=4*(lane>>4)+reg
  int dcol = w * 16 + (lane & 15);
#pragma unroll
  for (int reg = 0; reg < 4; ++reg) {
    int row = (lane >> 4) * 4 + reg;
    atomicAdd(&pacc[(R0 + row) * 128 + dcol], acc[reg]);
  }
}

// K3: out = elu(pacc / (0.9 * pz))
__global__ __launch_bounds__(256) void gat_final(
    const float* __restrict__ pacc, const float* __restrict__ pz,
    float* __restrict__ out) {
  int t = threadIdx.x;
  int row = blockIdx.x * 8 + (t >> 5);
  int d4 = (t & 31) * 4;
  float zinv = 1.f / (0.9f * pz[row]);
  float4 p = *(const float4*)&pacc[row * 128 + d4];
  float4 o;
  float v;
  v = p.x * zinv; o.x = v > 0.f ? v : expm1f(v);
  v = p.y * zinv; o.y = v > 0.f ? v : expm1f(v);
  v = p.z * zinv; o.z = v > 0.f ? v : expm1f(v);
  v = p.w * zinv; o.w = v > 0.f ? v : expm1f(v);
  *(float4*)&out[row * 128 + d4] = o;
}

extern "C" void kernel_launch(void* const* d_in, const int* in_sizes, int n_in,
                              void* d_out, int out_size, void* d_ws, size_t ws_size,
                              hipStream_t stream) {
  const float* batch = (const float*)d_in[0];
  const float* w = (const float*)d_in[1];
  const float* a = (const float*)d_in[2];
  float* out = (float*)d_out;
  char* ws = (char*)d_ws;
  // layout: [pacc 4MB][pz 32KB][s2key 64B pad][WhbT 2MB][s1 32KB][s2 32KB]
  float* pacc = (float*)ws;
  float* pz = (float*)(ws + 4194304);
  uint32_t* s2key = (uint32_t*)(ws + 4194304 + 32768);
  unsigned short* WhbT = (unsigned short*)(ws + 4194304 + 32768 + 64);
  float* s1 = (float*)(ws + 4194304 + 32768 + 64 + 2097152);
  float* s2 = (float*)(ws + 4194304 + 32768 + 64 + 2097152 + 32768);

  hipMemsetAsync(ws, 0, 4194304 + 32768 + 64, stream);  // pacc + pz + s2key
  wh_kernel<<<256, 256, 0, stream>>>(batch, w, a, WhbT, s1, s2, s2key);
  gat_main<<<1024, 512, 0, stream>>>(s1, s2, s2key, WhbT, pacc, pz);
  gat_final<<<1024, 256, 0, stream>>>(pacc, pz, out);
}